// Round 10
// baseline (635.606 us; speedup 1.0000x reference)
//
#include <hip/hip_runtime.h>

typedef _Float16 h2_t __attribute__((ext_vector_type(2)));

#define DI __device__ __forceinline__

constexpr int PA = 98;           // staged tile pitch (halfs): 49 dwords, odd
constexpr int PB = 66;           // hb pitch (halfs): 33 dwords, odd
constexpr int TILE = 64 * PA;    // staged x/y tile: 64 rows x 96 cols (6272 h)
constexpr int HB = 64 * PB;      // hb map: 64 cols x 64 rows (4224 h)
constexpr float kC1 = 1.0e-4f;   // (0.01*1)^2
constexpr float kC2 = 9.0e-4f;   // (0.03*1)^2
constexpr float kALPHA = 0.025f;

DI float rcp_fast(float v) { return __builtin_amdgcn_rcpf(v); }

DI float fdot2f(h2_t a, h2_t b, float c) {
#if __has_builtin(__builtin_amdgcn_fdot2)
  return __builtin_amdgcn_fdot2(a, b, c, false);   // v_dot2_f32_f16
#else
  return c + (float)(a.x) * (float)(b.x) + (float)(a.y) * (float)(b.y);
#endif
}

DI h2_t ldh2(const _Float16* __restrict__ p) {
  return *reinterpret_cast<const h2_t*>(p);
}
DI h2_t w2h(unsigned u) { return __builtin_bit_cast(h2_t, u); }
DI h2_t pkabs(h2_t v) {
  unsigned u = __builtin_bit_cast(unsigned, v) & 0x7FFF7FFFu;
  return __builtin_bit_cast(h2_t, u);
}

// ---- horizontal conv: src[row][col] -> hb[col][row], SINGLE map ----
// Group = 1 row x 8 stride-2 cols; window pairs adjacent -> fdot2.
// MODE 0: conv(v) from src.  MODE 1: conv(v^2) from src.
// MODE 2: conv(x*y) (src=xt, y at +TILE).  MODE 3: conv(|x-y|).
template<int R, int MODE>
DI void hconv(const _Float16* __restrict__ src, _Float16* __restrict__ hb,
              const unsigned* __restrict__ tabs, int tid) {
  constexpr int NR = 32 + 2 * R;           // rows produced: [16-R, 48+R)
  constexpr int NG = NR * 8;
  for (int g = tid; g < NG; g += 256) {
    const int row = (16 - R) + (g % NR);
    const int ci = g / NR;                 // 0..7
    const int c0 = ((ci >> 1) << 4) | (ci & 1);
    const int par = ci & 1;
    const unsigned* wt = tabs + (par ? 32 : 0);
    const int pbase = (c0 + 16 - R - par) >> 1;
    const _Float16* px = src + row * PA + 2 * pbase;
    float a[8];
#pragma unroll
    for (int i = 0; i < 8; ++i) a[i] = 0.f;
#pragma unroll
    for (int p = 0; p < R + 8; ++p) {
      h2_t xq = ldh2(px + 2 * p);
      h2_t v;
      if (MODE == 0) v = xq;
      else if (MODE == 1) v = xq * xq;                 // v_pk_mul_f16
      else {
        h2_t yq = ldh2(px + 2 * p + TILE);
        v = (MODE == 2) ? (xq * yq) : pkabs(xq - yq);
      }
#pragma unroll
      for (int i = 0; i < 8; ++i) {
        const int j = p - i;
        if (j >= 0 && j <= R)              // folds at compile time
          a[i] = fdot2f(w2h(wt[j]), v, a[i]);
      }
    }
    _Float16* wp = hb + c0 * PB + row;     // hb[col][row]
#pragma unroll
    for (int i = 0; i < 8; ++i) wp[i * (2 * PB)] = (_Float16)a[i];
  }
}

// ---- vertical conv: 1 col x 8 stride-2 rows per thread (8 outputs) ----
// col = tid&63 (64 lanes -> 64 cols, stride 33 dwords -> 2-way, free).
template<int R>
DI void vconv(const _Float16* __restrict__ hb, const unsigned* __restrict__ wt,
              int col, int pbase, float* __restrict__ acc) {
  const _Float16* p0 = hb + col * PB + 2 * pbase;
#pragma unroll
  for (int p = 0; p < R + 8; ++p) {
    h2_t v = ldh2(p0 + 2 * p);
#pragma unroll
    for (int m = 0; m < 8; ++m) {
      const int j = p - m;
      if (j >= 0 && j <= R)
        acc[m] = fdot2f(w2h(wt[j]), v, acc[m]);
    }
  }
}

// ---- vertical conv of |x-y| collapsed to scalar via uniform U table ----
template<int R>
DI float vl1(const _Float16* __restrict__ hb, const unsigned* __restrict__ Ut,
             int col, int pbase) {
  const _Float16* p0 = hb + col * PB + 2 * pbase;
  float s = 0.f;
#pragma unroll
  for (int p = 0; p < R + 8; ++p)
    s = fdot2f(w2h(Ut[p]), ldh2(p0 + 2 * p), s);
  return s;
}

// Single-hb per-sigma pipeline: 5 (6 for LAST) phases of hconv|bar|vconv|bar.
// All per-thread arrays 8-wide; design liveness ~80 regs < 128 cap.
template<int R, bool LAST>
DI void do_sigma(int sidx, const unsigned* __restrict__ tabs0,
                 const _Float16* __restrict__ xt, _Float16* __restrict__ hb,
                 float* __restrict__ PIcs, float& gl1s, int tid) {
  const unsigned* tabs = tabs0 + sidx * 64;
  const int col = tid & 63, q = tid >> 6;  // q: 0..3
  const int par = q & 1, hh = q >> 1;
  const unsigned* wt = tabs + (par ? 32 : 0);
  const int pbase = 8 * hh + (16 - R) / 2;

  float mux[8], muy[8], s2[8];
#pragma unroll
  for (int i = 0; i < 8; ++i) { mux[i] = 0.f; muy[i] = 0.f; s2[i] = 0.f; }

  hconv<R, 0>(xt, hb, tabs, tid);          // h(x)
  __syncthreads();
  vconv<R>(hb, wt, col, pbase, mux);
  __syncthreads();
  hconv<R, 1>(xt, hb, tabs, tid);          // h(x^2)
  __syncthreads();
  vconv<R>(hb, wt, col, pbase, s2);
  __syncthreads();
  hconv<R, 0>(xt + TILE, hb, tabs, tid);   // h(y)
  __syncthreads();
  vconv<R>(hb, wt, col, pbase, muy);
  __syncthreads();
  hconv<R, 1>(xt + TILE, hb, tabs, tid);   // h(y^2)
  __syncthreads();
  vconv<R>(hb, wt, col, pbase, s2);        // s2 = E[x^2]+E[y^2]
  __syncthreads();
  // fold in place: mux <- mxy, muy <- rden
#pragma unroll
  for (int i = 0; i < 8; ++i) {
    float a = mux[i], b = muy[i];
    float m2 = a * a + b * b;
    mux[i] = a * b;                        // mxy
    muy[i] = rcp_fast(s2[i] - m2 + kC2);   // rden
    if (LAST)                              // luminance folded into PIcs
      PIcs[i] *= fmaf(2.f, mux[i], kC1) * rcp_fast(m2 + kC1);
  }
  hconv<R, 2>(xt, hb, tabs, tid);          // h(x*y)
  __syncthreads();
  float exy[8];
#pragma unroll
  for (int i = 0; i < 8; ++i) exy[i] = 0.f;
  vconv<R>(hb, wt, col, pbase, exy);
  __syncthreads();
#pragma unroll
  for (int i = 0; i < 8; ++i)
    PIcs[i] *= fmaf(2.f, exy[i] - mux[i], kC2) * muy[i];
  if (LAST) {
    hconv<R, 3>(xt, hb, tabs, tid);        // h(|x-y|)
    __syncthreads();
    gl1s += vl1<R>(hb, tabs0 + 320 + (par ? 24 : 0), col, pbase);
    __syncthreads();
  }
}

DI unsigned packh(float a, float b) {
  h2_t v; v.x = (_Float16)a; v.y = (_Float16)b;
  return __builtin_bit_cast(unsigned, v);
}

// ws: [0..164] f32 1D kernels; u32 tabs at +165: per sigma s: E @s*64+[0..R],
// O @s*64+32+[0..R]; l1-collapse U tables (R=16): UE @320+[0..23], UO @344.
__global__ void prep_k(const float* __restrict__ gm, float* __restrict__ ws) {
  int t = threadIdx.x;
  if (t < 165) {
    int s = t / 33, j = t % 33;
    const float* m = gm + (3 * s) * (33 * 33);
    ws[t] = m[16 * 33 + j] / sqrtf(m[16 * 33 + 16]);
  }
  __syncthreads();
  if (t == 0) {
    unsigned* tabs = (unsigned*)(ws + 165);
    const int Rs[5] = {4, 6, 12, 16, 16};
    for (int s = 0; s < 5; ++s) {
      const int R = Rs[s];
      const float* w = ws + s * 33 + (16 - R);   // K = 2R+1 taps
      unsigned* E = tabs + s * 64;
      unsigned* O = E + 32;
      for (int i = 0; i < R; ++i) E[i] = packh(w[2 * i], w[2 * i + 1]);
      E[R] = packh(w[2 * R], 0.f);
      O[0] = packh(0.f, w[0]);
      for (int i = 1; i <= R; ++i) O[i] = packh(w[2 * i - 1], w[2 * i]);
    }
    // U tables: sum over m=0..7 of the E/O entry at j=p-m (f32, then pack)
    const float* w = ws + 4 * 33;                // sigma=8, R=16, wk = w
    for (int par = 0; par < 2; ++par) {
      unsigned* U = tabs + 320 + par * 24;
      for (int p = 0; p < 24; ++p) {
        float ux = 0.f, uy = 0.f;
        for (int m = 0; m < 8; ++m) {
          int j = p - m;
          if (j < 0 || j > 16) continue;
          if (par == 0) {
            ux += w[2 * j];
            if (2 * j + 1 <= 32) uy += w[2 * j + 1];
          } else {
            if (2 * j - 1 >= 0) ux += w[2 * j - 1];
            uy += w[2 * j];
          }
        }
        U[p] = packh(ux, uy);
      }
    }
  }
}

// 64x32 output tile, 33.5 KB LDS -> 4 blocks/CU; (256,4) caps VGPR at 128.
__global__ __launch_bounds__(256, 4)
void msloss_k(const float* __restrict__ x, const float* __restrict__ y,
              const float* __restrict__ ws, float* __restrict__ out) {
  // xt @0 [row][col] (64x96), yt @TILE, hb @2*TILE [col][row] (64x64)
  __shared__ __align__(16) _Float16 smem[2 * TILE + HB];
  __shared__ float red[4];
  _Float16* xt = smem;
  _Float16* hb = smem + 2 * TILE;
  const unsigned* tabs0 = (const unsigned*)(ws + 165);
  const int tid = threadIdx.x;
  const int ox = blockIdx.x * 64, oy = blockIdx.y * 32;
  const int b = blockIdx.z;

  float PIcs[8];
  float gl1s = 0.f;
#pragma unroll
  for (int i = 0; i < 8; ++i) PIcs[i] = 1.f;

  for (int c = 0; c < 3; ++c) {
    const float* xp = x + (size_t)(b * 3 + c) * (512 * 512);
    const float* yp = y + (size_t)(b * 3 + c) * (512 * 512);
    // stage 64 rows x 96 cols fp32 -> fp16, [row][col], zero halo
#pragma unroll
    for (int it = 0; it < 12; ++it) {
      int idx = it * 256 + tid;            // 64 rows x 48 colpairs
      int row = idx / 48, cp = idx % 48;
      int gy = oy + row - 16, gx = ox + cp * 2 - 16;
      bool ok = ((unsigned)gy < 512u) && ((unsigned)gx < 512u);  // gx even
      float2 xv = make_float2(0.f, 0.f), yv = make_float2(0.f, 0.f);
      if (ok) {
        xv = *reinterpret_cast<const float2*>(xp + gy * 512 + gx);
        yv = *reinterpret_cast<const float2*>(yp + gy * 512 + gx);
      }
      h2_t hx; hx.x = (_Float16)xv.x; hx.y = (_Float16)xv.y;
      h2_t hy; hy.x = (_Float16)yv.x; hy.y = (_Float16)yv.y;
      *reinterpret_cast<h2_t*>(xt + row * PA + cp * 2) = hx;
      *reinterpret_cast<h2_t*>(xt + TILE + row * PA + cp * 2) = hy;
    }
    __syncthreads();
    do_sigma<4,  false>(0, tabs0, xt, hb, PIcs, gl1s, tid);
    do_sigma<6,  false>(1, tabs0, xt, hb, PIcs, gl1s, tid);
    do_sigma<12, false>(2, tabs0, xt, hb, PIcs, gl1s, tid);
    do_sigma<16, false>(3, tabs0, xt, hb, PIcs, gl1s, tid);
    do_sigma<16, true >(4, tabs0, xt, hb, PIcs, gl1s, tid);
    // do_sigma ends with __syncthreads(): safe to restage next channel
  }

  float s = ((1.f - kALPHA) / 3.f) * gl1s;
#pragma unroll
  for (int i = 0; i < 8; ++i) s += kALPHA * (1.f - PIcs[i]);
#pragma unroll
  for (int off = 32; off > 0; off >>= 1) s += __shfl_down(s, off);
  if ((tid & 63) == 0) red[tid >> 6] = s;
  __syncthreads();
  if (tid == 0)
    atomicAdd(out, (red[0] + red[1] + red[2] + red[3]) *
                       (200.0f / (8.0f * 512.0f * 512.0f)));
}

extern "C" void kernel_launch(void* const* d_in, const int* in_sizes, int n_in,
                              void* d_out, int out_size, void* d_ws, size_t ws_size,
                              hipStream_t stream) {
  const float* x = (const float*)d_in[0];
  const float* y = (const float*)d_in[1];
  const float* gm = (const float*)d_in[2];
  float* out = (float*)d_out;
  float* ws = (float*)d_ws;   // 165 f32 + packed half2 tables (~2.1 KB)

  hipMemsetAsync(d_out, 0, out_size * sizeof(float), stream);
  prep_k<<<1, 256, 0, stream>>>(gm, ws);
  msloss_k<<<dim3(8, 16, 8), 256, 0, stream>>>(x, y, ws, out);
}

// Round 11
// 552.082 us; speedup vs baseline: 1.1513x; 1.1513x over previous
//
#include <hip/hip_runtime.h>

typedef _Float16 h2_t __attribute__((ext_vector_type(2)));

#define DI __device__ __forceinline__

constexpr int PA = 98;           // staged tile pitch (halfs): 49 dwords, odd
constexpr int PB = 66;           // hb pitch (halfs): 33 dwords, odd
constexpr int TILE = 64 * PA;    // staged x/y tile: 64 rows x 96 cols (6272 h)
constexpr int HB = 64 * PB;      // hb map: 64 cols x 64 rows (4224 h)
constexpr float kC1 = 1.0e-4f;   // (0.01*1)^2
constexpr float kC2 = 9.0e-4f;   // (0.03*1)^2
constexpr float kALPHA = 0.025f;

DI float rcp_fast(float v) { return __builtin_amdgcn_rcpf(v); }

DI float fdot2f(h2_t a, h2_t b, float c) {
#if __has_builtin(__builtin_amdgcn_fdot2)
  return __builtin_amdgcn_fdot2(a, b, c, false);   // v_dot2_f32_f16
#else
  return c + (float)(a.x) * (float)(b.x) + (float)(a.y) * (float)(b.y);
#endif
}

DI h2_t ldh2(const _Float16* __restrict__ p) {
  return *reinterpret_cast<const h2_t*>(p);
}
DI h2_t w2h(unsigned u) { return __builtin_bit_cast(h2_t, u); }
DI h2_t pkabs(h2_t v) {
  unsigned u = __builtin_bit_cast(unsigned, v) & 0x7FFF7FFFu;
  return __builtin_bit_cast(h2_t, u);
}

// ---- horizontal conv: src[row][col] -> hb[col][row], SINGLE map ----
// Group = 1 row x 8 stride-2 cols; window pairs adjacent -> fdot2.
// MODE 0: conv(v) from src.  MODE 1: conv(v^2) from src.
// MODE 2: conv(x*y) (src=xt, y at +TILE).  MODE 3: conv(|x-y|).
template<int R, int MODE>
DI void hconv(const _Float16* __restrict__ src, _Float16* __restrict__ hb,
              const unsigned* __restrict__ tabs, int tid) {
  constexpr int NR = 32 + 2 * R;           // rows produced: [16-R, 48+R)
  constexpr int NG = NR * 8;
  for (int g = tid; g < NG; g += 256) {
    const int row = (16 - R) + (g % NR);
    const int ci = g / NR;                 // 0..7
    const int c0 = ((ci >> 1) << 4) | (ci & 1);
    const int par = ci & 1;
    const unsigned* wt = tabs + (par ? 32 : 0);
    const int pbase = (c0 + 16 - R - par) >> 1;
    const _Float16* px = src + row * PA + 2 * pbase;
    float a[8];
#pragma unroll
    for (int i = 0; i < 8; ++i) a[i] = 0.f;
#pragma unroll
    for (int p = 0; p < R + 8; ++p) {
      h2_t xq = ldh2(px + 2 * p);
      h2_t v;
      if (MODE == 0) v = xq;
      else if (MODE == 1) v = xq * xq;                 // v_pk_mul_f16
      else {
        h2_t yq = ldh2(px + 2 * p + TILE);
        v = (MODE == 2) ? (xq * yq) : pkabs(xq - yq);
      }
#pragma unroll
      for (int i = 0; i < 8; ++i) {
        const int j = p - i;
        if (j >= 0 && j <= R)              // folds at compile time
          a[i] = fdot2f(w2h(wt[j]), v, a[i]);
      }
    }
    _Float16* wp = hb + c0 * PB + row;     // hb[col][row]
#pragma unroll
    for (int i = 0; i < 8; ++i) wp[i * (2 * PB)] = (_Float16)a[i];
  }
}

// ---- vertical conv: 1 col x 8 stride-2 rows per thread (8 outputs) ----
// col = tid&63 (64 lanes -> 64 cols, stride 33 dwords -> 2-way, free).
template<int R>
DI void vconv(const _Float16* __restrict__ hb, const unsigned* __restrict__ wt,
              int col, int pbase, float* __restrict__ acc) {
  const _Float16* p0 = hb + col * PB + 2 * pbase;
#pragma unroll
  for (int p = 0; p < R + 8; ++p) {
    h2_t v = ldh2(p0 + 2 * p);
#pragma unroll
    for (int m = 0; m < 8; ++m) {
      const int j = p - m;
      if (j >= 0 && j <= R)
        acc[m] = fdot2f(w2h(wt[j]), v, acc[m]);
    }
  }
}

// ---- vertical conv of |x-y| collapsed to scalar via uniform U table ----
template<int R>
DI float vl1(const _Float16* __restrict__ hb, const unsigned* __restrict__ Ut,
             int col, int pbase) {
  const _Float16* p0 = hb + col * PB + 2 * pbase;
  float s = 0.f;
#pragma unroll
  for (int p = 0; p < R + 8; ++p)
    s = fdot2f(w2h(Ut[p]), ldh2(p0 + 2 * p), s);
  return s;
}

// Single-hb per-sigma pipeline: 5 (6 for LAST) phases of hconv|bar|vconv|bar.
// All per-thread arrays 8-wide; design liveness ~80 regs < 128 cap.
template<int R, bool LAST>
DI void do_sigma(int sidx, const unsigned* __restrict__ tabs0,
                 const _Float16* __restrict__ xt, _Float16* __restrict__ hb,
                 float* __restrict__ PIcs, float& gl1s, int tid) {
  const unsigned* tabs = tabs0 + sidx * 64;
  const int col = tid & 63, q = tid >> 6;  // q: 0..3
  const int par = q & 1, hh = q >> 1;
  const unsigned* wt = tabs + (par ? 32 : 0);
  const int pbase = 8 * hh + (16 - R) / 2;

  float mux[8], muy[8], s2[8];
#pragma unroll
  for (int i = 0; i < 8; ++i) { mux[i] = 0.f; muy[i] = 0.f; s2[i] = 0.f; }

  hconv<R, 0>(xt, hb, tabs, tid);          // h(x)
  __syncthreads();
  vconv<R>(hb, wt, col, pbase, mux);
  __syncthreads();
  hconv<R, 1>(xt, hb, tabs, tid);          // h(x^2)
  __syncthreads();
  vconv<R>(hb, wt, col, pbase, s2);
  __syncthreads();
  hconv<R, 0>(xt + TILE, hb, tabs, tid);   // h(y)
  __syncthreads();
  vconv<R>(hb, wt, col, pbase, muy);
  __syncthreads();
  hconv<R, 1>(xt + TILE, hb, tabs, tid);   // h(y^2)
  __syncthreads();
  vconv<R>(hb, wt, col, pbase, s2);        // s2 = E[x^2]+E[y^2]
  __syncthreads();
  // fold in place: mux <- mxy, muy <- rden
#pragma unroll
  for (int i = 0; i < 8; ++i) {
    float a = mux[i], b = muy[i];
    float m2 = a * a + b * b;
    mux[i] = a * b;                        // mxy
    muy[i] = rcp_fast(s2[i] - m2 + kC2);   // rden
    if (LAST)                              // luminance folded into PIcs
      PIcs[i] *= fmaf(2.f, mux[i], kC1) * rcp_fast(m2 + kC1);
  }
  hconv<R, 2>(xt, hb, tabs, tid);          // h(x*y)
  __syncthreads();
  float exy[8];
#pragma unroll
  for (int i = 0; i < 8; ++i) exy[i] = 0.f;
  vconv<R>(hb, wt, col, pbase, exy);
  __syncthreads();
#pragma unroll
  for (int i = 0; i < 8; ++i)
    PIcs[i] *= fmaf(2.f, exy[i] - mux[i], kC2) * muy[i];
  if (LAST) {
    hconv<R, 3>(xt, hb, tabs, tid);        // h(|x-y|)
    __syncthreads();
    gl1s += vl1<R>(hb, tabs0 + 320 + (par ? 24 : 0), col, pbase);
    __syncthreads();
  }
}

DI unsigned packh(float a, float b) {
  h2_t v; v.x = (_Float16)a; v.y = (_Float16)b;
  return __builtin_bit_cast(unsigned, v);
}

// ws: [0..164] f32 1D kernels; u32 tabs at +165: per sigma s: E @s*64+[0..R],
// O @s*64+32+[0..R]; l1-collapse U tables (R=16): UE @320+[0..23], UO @344.
__global__ void prep_k(const float* __restrict__ gm, float* __restrict__ ws) {
  int t = threadIdx.x;
  if (t < 165) {
    int s = t / 33, j = t % 33;
    const float* m = gm + (3 * s) * (33 * 33);
    ws[t] = m[16 * 33 + j] / sqrtf(m[16 * 33 + 16]);
  }
  __syncthreads();
  if (t == 0) {
    unsigned* tabs = (unsigned*)(ws + 165);
    const int Rs[5] = {4, 6, 12, 16, 16};
    for (int s = 0; s < 5; ++s) {
      const int R = Rs[s];
      const float* w = ws + s * 33 + (16 - R);   // K = 2R+1 taps
      unsigned* E = tabs + s * 64;
      unsigned* O = E + 32;
      for (int i = 0; i < R; ++i) E[i] = packh(w[2 * i], w[2 * i + 1]);
      E[R] = packh(w[2 * R], 0.f);
      O[0] = packh(0.f, w[0]);
      for (int i = 1; i <= R; ++i) O[i] = packh(w[2 * i - 1], w[2 * i]);
    }
    // U tables: sum over m=0..7 of the E/O entry at j=p-m (f32, then pack)
    const float* w = ws + 4 * 33;                // sigma=8, R=16, wk = w
    for (int par = 0; par < 2; ++par) {
      unsigned* U = tabs + 320 + par * 24;
      for (int p = 0; p < 24; ++p) {
        float ux = 0.f, uy = 0.f;
        for (int m = 0; m < 8; ++m) {
          int j = p - m;
          if (j < 0 || j > 16) continue;
          if (par == 0) {
            ux += w[2 * j];
            if (2 * j + 1 <= 32) uy += w[2 * j + 1];
          } else {
            if (2 * j - 1 >= 0) ux += w[2 * j - 1];
            uy += w[2 * j];
          }
        }
        U[p] = packh(ux, uy);
      }
    }
  }
}

// 64x32 output tile, 33.8 KB LDS -> 4 blocks/CU. __launch_bounds__(256,2):
// empirical VGPR cap = 256/minwaves (R0:2->128, R8:none->256, R10:4->64);
// 128 fits the ~80-live design (no spill) AND still permits 4 waves/EU.
__global__ __launch_bounds__(256, 2)
void msloss_k(const float* __restrict__ x, const float* __restrict__ y,
              const float* __restrict__ ws, float* __restrict__ out) {
  // xt @0 [row][col] (64x96), yt @TILE, hb @2*TILE [col][row] (64x64)
  __shared__ __align__(16) _Float16 smem[2 * TILE + HB];
  __shared__ float red[4];
  _Float16* xt = smem;
  _Float16* hb = smem + 2 * TILE;
  const unsigned* tabs0 = (const unsigned*)(ws + 165);
  const int tid = threadIdx.x;
  const int ox = blockIdx.x * 64, oy = blockIdx.y * 32;
  const int b = blockIdx.z;

  float PIcs[8];
  float gl1s = 0.f;
#pragma unroll
  for (int i = 0; i < 8; ++i) PIcs[i] = 1.f;

  for (int c = 0; c < 3; ++c) {
    const float* xp = x + (size_t)(b * 3 + c) * (512 * 512);
    const float* yp = y + (size_t)(b * 3 + c) * (512 * 512);
    // stage 64 rows x 96 cols fp32 -> fp16, [row][col], zero halo
#pragma unroll
    for (int it = 0; it < 12; ++it) {
      int idx = it * 256 + tid;            // 64 rows x 48 colpairs
      int row = idx / 48, cp = idx % 48;
      int gy = oy + row - 16, gx = ox + cp * 2 - 16;
      bool ok = ((unsigned)gy < 512u) && ((unsigned)gx < 512u);  // gx even
      float2 xv = make_float2(0.f, 0.f), yv = make_float2(0.f, 0.f);
      if (ok) {
        xv = *reinterpret_cast<const float2*>(xp + gy * 512 + gx);
        yv = *reinterpret_cast<const float2*>(yp + gy * 512 + gx);
      }
      h2_t hx; hx.x = (_Float16)xv.x; hx.y = (_Float16)xv.y;
      h2_t hy; hy.x = (_Float16)yv.x; hy.y = (_Float16)yv.y;
      *reinterpret_cast<h2_t*>(xt + row * PA + cp * 2) = hx;
      *reinterpret_cast<h2_t*>(xt + TILE + row * PA + cp * 2) = hy;
    }
    __syncthreads();
    do_sigma<4,  false>(0, tabs0, xt, hb, PIcs, gl1s, tid);
    do_sigma<6,  false>(1, tabs0, xt, hb, PIcs, gl1s, tid);
    do_sigma<12, false>(2, tabs0, xt, hb, PIcs, gl1s, tid);
    do_sigma<16, false>(3, tabs0, xt, hb, PIcs, gl1s, tid);
    do_sigma<16, true >(4, tabs0, xt, hb, PIcs, gl1s, tid);
    // do_sigma ends with __syncthreads(): safe to restage next channel
  }

  float s = ((1.f - kALPHA) / 3.f) * gl1s;
#pragma unroll
  for (int i = 0; i < 8; ++i) s += kALPHA * (1.f - PIcs[i]);
#pragma unroll
  for (int off = 32; off > 0; off >>= 1) s += __shfl_down(s, off);
  if ((tid & 63) == 0) red[tid >> 6] = s;
  __syncthreads();
  if (tid == 0)
    atomicAdd(out, (red[0] + red[1] + red[2] + red[3]) *
                       (200.0f / (8.0f * 512.0f * 512.0f)));
}

extern "C" void kernel_launch(void* const* d_in, const int* in_sizes, int n_in,
                              void* d_out, int out_size, void* d_ws, size_t ws_size,
                              hipStream_t stream) {
  const float* x = (const float*)d_in[0];
  const float* y = (const float*)d_in[1];
  const float* gm = (const float*)d_in[2];
  float* out = (float*)d_out;
  float* ws = (float*)d_ws;   // 165 f32 + packed half2 tables (~2.1 KB)

  hipMemsetAsync(d_out, 0, out_size * sizeof(float), stream);
  prep_k<<<1, 256, 0, stream>>>(gm, ws);
  msloss_k<<<dim3(8, 16, 8), 256, 0, stream>>>(x, y, ws, out);
}

// Round 12
// 540.822 us; speedup vs baseline: 1.1753x; 1.0208x over previous
//
#include <hip/hip_runtime.h>

typedef _Float16 h2_t __attribute__((ext_vector_type(2)));

#define DI __device__ __forceinline__

#if __has_builtin(__builtin_amdgcn_sched_barrier)
#define SCHED_FENCE() __builtin_amdgcn_sched_barrier(0)
#else
#define SCHED_FENCE()
#endif

constexpr int PA = 98;           // staged tile pitch (halfs): 49 dwords, odd
constexpr int PB = 66;           // hb pitch (halfs): 33 dwords, odd
constexpr int TILE = 64 * PA;    // staged x/y tile: 64 rows x 96 cols (6272 h)
constexpr int HB = 64 * PB;      // hb map: 64 cols x 64 rows (4224 h)
constexpr float kC1 = 1.0e-4f;   // (0.01*1)^2
constexpr float kC2 = 9.0e-4f;   // (0.03*1)^2
constexpr float kALPHA = 0.025f;

DI float rcp_fast(float v) { return __builtin_amdgcn_rcpf(v); }

DI float fdot2f(h2_t a, h2_t b, float c) {
#if __has_builtin(__builtin_amdgcn_fdot2)
  return __builtin_amdgcn_fdot2(a, b, c, false);   // v_dot2_f32_f16
#else
  return c + (float)(a.x) * (float)(b.x) + (float)(a.y) * (float)(b.y);
#endif
}

DI h2_t ldh2(const _Float16* __restrict__ p) {
  return *reinterpret_cast<const h2_t*>(p);
}
DI h2_t w2h(unsigned u) { return __builtin_bit_cast(h2_t, u); }
DI h2_t pkabs(h2_t v) {
  unsigned u = __builtin_bit_cast(unsigned, v) & 0x7FFF7FFFu;
  return __builtin_bit_cast(h2_t, u);
}

// ---- horizontal conv: src[row][col] -> hb[col][row], SINGLE map ----
// Group = 1 row x 8 stride-2 cols; window pairs adjacent -> fdot2.
// SCHED_FENCE every 8 taps: caps the scheduler's ds_read hoisting window
// (R11 spilled 238 MB at VGPR=128 because up to 24-48 independent loads
// were batched ahead of the FMA stream -> transient liveness > cap).
// MODE 0: conv(v).  MODE 1: conv(v^2).  MODE 2: conv(x*y).  MODE 3: conv(|x-y|).
template<int R, int MODE>
DI void hconv(const _Float16* __restrict__ src, _Float16* __restrict__ hb,
              const unsigned* __restrict__ tabs, int tid) {
  constexpr int NR = 32 + 2 * R;           // rows produced: [16-R, 48+R)
  constexpr int NG = NR * 8;
  for (int g = tid; g < NG; g += 256) {
    const int row = (16 - R) + (g % NR);
    const int ci = g / NR;                 // 0..7
    const int c0 = ((ci >> 1) << 4) | (ci & 1);
    const int par = ci & 1;
    const unsigned* wt = tabs + (par ? 32 : 0);
    const int pbase = (c0 + 16 - R - par) >> 1;
    const _Float16* px = src + row * PA + 2 * pbase;
    float a[8];
#pragma unroll
    for (int i = 0; i < 8; ++i) a[i] = 0.f;
#pragma unroll
    for (int p = 0; p < R + 8; ++p) {
      h2_t xq = ldh2(px + 2 * p);
      h2_t v;
      if (MODE == 0) v = xq;
      else if (MODE == 1) v = xq * xq;                 // v_pk_mul_f16
      else {
        h2_t yq = ldh2(px + 2 * p + TILE);
        v = (MODE == 2) ? (xq * yq) : pkabs(xq - yq);
      }
#pragma unroll
      for (int i = 0; i < 8; ++i) {
        const int j = p - i;
        if (j >= 0 && j <= R)              // folds at compile time
          a[i] = fdot2f(w2h(wt[j]), v, a[i]);
      }
      if ((p & 7) == 7) SCHED_FENCE();
    }
    _Float16* wp = hb + c0 * PB + row;     // hb[col][row]
#pragma unroll
    for (int i = 0; i < 8; ++i) wp[i * (2 * PB)] = (_Float16)a[i];
  }
}

// ---- vertical conv: 1 col x 8 stride-2 rows per thread (8 outputs) ----
// col = tid&63 (64 lanes -> 64 cols, stride 33 dwords -> 2-way, free).
template<int R>
DI void vconv(const _Float16* __restrict__ hb, const unsigned* __restrict__ wt,
              int col, int pbase, float* __restrict__ acc) {
  const _Float16* p0 = hb + col * PB + 2 * pbase;
#pragma unroll
  for (int p = 0; p < R + 8; ++p) {
    h2_t v = ldh2(p0 + 2 * p);
#pragma unroll
    for (int m = 0; m < 8; ++m) {
      const int j = p - m;
      if (j >= 0 && j <= R)
        acc[m] = fdot2f(w2h(wt[j]), v, acc[m]);
    }
    if ((p & 7) == 7) SCHED_FENCE();
  }
}

// ---- vertical conv of |x-y| collapsed to scalar via uniform U table ----
template<int R>
DI float vl1(const _Float16* __restrict__ hb, const unsigned* __restrict__ Ut,
             int col, int pbase) {
  const _Float16* p0 = hb + col * PB + 2 * pbase;
  float s = 0.f;
#pragma unroll
  for (int p = 0; p < R + 8; ++p) {
    s = fdot2f(w2h(Ut[p]), ldh2(p0 + 2 * p), s);
    if ((p & 7) == 7) SCHED_FENCE();
  }
  return s;
}

// Single-hb per-sigma pipeline: 5 (6 for LAST) phases of hconv|bar|vconv|bar.
template<int R, bool LAST>
DI void do_sigma(int sidx, const unsigned* __restrict__ tabs0,
                 const _Float16* __restrict__ xt, _Float16* __restrict__ hb,
                 float* __restrict__ PIcs, float& gl1s, int tid) {
  const unsigned* tabs = tabs0 + sidx * 64;
  const int col = tid & 63, q = tid >> 6;  // q: 0..3
  const int par = q & 1, hh = q >> 1;
  const unsigned* wt = tabs + (par ? 32 : 0);
  const int pbase = 8 * hh + (16 - R) / 2;

  float mux[8], muy[8], s2[8];
#pragma unroll
  for (int i = 0; i < 8; ++i) { mux[i] = 0.f; muy[i] = 0.f; s2[i] = 0.f; }

  hconv<R, 0>(xt, hb, tabs, tid);          // h(x)
  __syncthreads();
  vconv<R>(hb, wt, col, pbase, mux);
  __syncthreads();
  hconv<R, 1>(xt, hb, tabs, tid);          // h(x^2)
  __syncthreads();
  vconv<R>(hb, wt, col, pbase, s2);
  __syncthreads();
  hconv<R, 0>(xt + TILE, hb, tabs, tid);   // h(y)
  __syncthreads();
  vconv<R>(hb, wt, col, pbase, muy);
  __syncthreads();
  hconv<R, 1>(xt + TILE, hb, tabs, tid);   // h(y^2)
  __syncthreads();
  vconv<R>(hb, wt, col, pbase, s2);        // s2 = E[x^2]+E[y^2]
  __syncthreads();
  // fold in place: mux <- mxy, muy <- rden
#pragma unroll
  for (int i = 0; i < 8; ++i) {
    float a = mux[i], b = muy[i];
    float m2 = a * a + b * b;
    mux[i] = a * b;                        // mxy
    muy[i] = rcp_fast(s2[i] - m2 + kC2);   // rden
    if (LAST)                              // luminance folded into PIcs
      PIcs[i] *= fmaf(2.f, mux[i], kC1) * rcp_fast(m2 + kC1);
  }
  hconv<R, 2>(xt, hb, tabs, tid);          // h(x*y)
  __syncthreads();
  float exy[8];
#pragma unroll
  for (int i = 0; i < 8; ++i) exy[i] = 0.f;
  vconv<R>(hb, wt, col, pbase, exy);
  __syncthreads();
#pragma unroll
  for (int i = 0; i < 8; ++i)
    PIcs[i] *= fmaf(2.f, exy[i] - mux[i], kC2) * muy[i];
  if (LAST) {
    hconv<R, 3>(xt, hb, tabs, tid);        // h(|x-y|)
    __syncthreads();
    gl1s += vl1<R>(hb, tabs0 + 320 + (par ? 24 : 0), col, pbase);
    __syncthreads();
  }
}

DI unsigned packh(float a, float b) {
  h2_t v; v.x = (_Float16)a; v.y = (_Float16)b;
  return __builtin_bit_cast(unsigned, v);
}

// ws: [0..164] f32 1D kernels; u32 tabs at +165: per sigma s: E @s*64+[0..R],
// O @s*64+32+[0..R]; l1-collapse U tables (R=16): UE @320+[0..23], UO @344.
__global__ void prep_k(const float* __restrict__ gm, float* __restrict__ ws) {
  int t = threadIdx.x;
  if (t < 165) {
    int s = t / 33, j = t % 33;
    const float* m = gm + (3 * s) * (33 * 33);
    ws[t] = m[16 * 33 + j] / sqrtf(m[16 * 33 + 16]);
  }
  __syncthreads();
  if (t == 0) {
    unsigned* tabs = (unsigned*)(ws + 165);
    const int Rs[5] = {4, 6, 12, 16, 16};
    for (int s = 0; s < 5; ++s) {
      const int R = Rs[s];
      const float* w = ws + s * 33 + (16 - R);   // K = 2R+1 taps
      unsigned* E = tabs + s * 64;
      unsigned* O = E + 32;
      for (int i = 0; i < R; ++i) E[i] = packh(w[2 * i], w[2 * i + 1]);
      E[R] = packh(w[2 * R], 0.f);
      O[0] = packh(0.f, w[0]);
      for (int i = 1; i <= R; ++i) O[i] = packh(w[2 * i - 1], w[2 * i]);
    }
    // U tables: sum over m=0..7 of the E/O entry at j=p-m (f32, then pack)
    const float* w = ws + 4 * 33;                // sigma=8, R=16, wk = w
    for (int par = 0; par < 2; ++par) {
      unsigned* U = tabs + 320 + par * 24;
      for (int p = 0; p < 24; ++p) {
        float ux = 0.f, uy = 0.f;
        for (int m = 0; m < 8; ++m) {
          int j = p - m;
          if (j < 0 || j > 16) continue;
          if (par == 0) {
            ux += w[2 * j];
            if (2 * j + 1 <= 32) uy += w[2 * j + 1];
          } else {
            if (2 * j - 1 >= 0) ux += w[2 * j - 1];
            uy += w[2 * j];
          }
        }
        U[p] = packh(ux, uy);
      }
    }
  }
}

// 64x32 output tile, 33.8 KB LDS -> 4 blocks/CU. (256,2) -> VGPR cap 128
// (confirmed: cap = 256/minwaves). SCHED_FENCE bounds transient liveness.
__global__ __launch_bounds__(256, 2)
void msloss_k(const float* __restrict__ x, const float* __restrict__ y,
              const float* __restrict__ ws, float* __restrict__ out) {
  // xt @0 [row][col] (64x96), yt @TILE, hb @2*TILE [col][row] (64x64)
  __shared__ __align__(16) _Float16 smem[2 * TILE + HB];
  __shared__ float red[4];
  _Float16* xt = smem;
  _Float16* hb = smem + 2 * TILE;
  const unsigned* tabs0 = (const unsigned*)(ws + 165);
  const int tid = threadIdx.x;
  const int ox = blockIdx.x * 64, oy = blockIdx.y * 32;
  const int b = blockIdx.z;

  float PIcs[8];
  float gl1s = 0.f;
#pragma unroll
  for (int i = 0; i < 8; ++i) PIcs[i] = 1.f;

  for (int c = 0; c < 3; ++c) {
    const float* xp = x + (size_t)(b * 3 + c) * (512 * 512);
    const float* yp = y + (size_t)(b * 3 + c) * (512 * 512);
    // stage 64 rows x 96 cols fp32 -> fp16, [row][col], zero halo
#pragma unroll
    for (int it = 0; it < 12; ++it) {
      int idx = it * 256 + tid;            // 64 rows x 48 colpairs
      int row = idx / 48, cp = idx % 48;
      int gy = oy + row - 16, gx = ox + cp * 2 - 16;
      bool ok = ((unsigned)gy < 512u) && ((unsigned)gx < 512u);  // gx even
      float2 xv = make_float2(0.f, 0.f), yv = make_float2(0.f, 0.f);
      if (ok) {
        xv = *reinterpret_cast<const float2*>(xp + gy * 512 + gx);
        yv = *reinterpret_cast<const float2*>(yp + gy * 512 + gx);
      }
      h2_t hx; hx.x = (_Float16)xv.x; hx.y = (_Float16)xv.y;
      h2_t hy; hy.x = (_Float16)yv.x; hy.y = (_Float16)yv.y;
      *reinterpret_cast<h2_t*>(xt + row * PA + cp * 2) = hx;
      *reinterpret_cast<h2_t*>(xt + TILE + row * PA + cp * 2) = hy;
    }
    __syncthreads();
    do_sigma<4,  false>(0, tabs0, xt, hb, PIcs, gl1s, tid);
    do_sigma<6,  false>(1, tabs0, xt, hb, PIcs, gl1s, tid);
    do_sigma<12, false>(2, tabs0, xt, hb, PIcs, gl1s, tid);
    do_sigma<16, false>(3, tabs0, xt, hb, PIcs, gl1s, tid);
    do_sigma<16, true >(4, tabs0, xt, hb, PIcs, gl1s, tid);
    // do_sigma ends with __syncthreads(): safe to restage next channel
  }

  float s = ((1.f - kALPHA) / 3.f) * gl1s;
#pragma unroll
  for (int i = 0; i < 8; ++i) s += kALPHA * (1.f - PIcs[i]);
#pragma unroll
  for (int off = 32; off > 0; off >>= 1) s += __shfl_down(s, off);
  if ((tid & 63) == 0) red[tid >> 6] = s;
  __syncthreads();
  if (tid == 0)
    atomicAdd(out, (red[0] + red[1] + red[2] + red[3]) *
                       (200.0f / (8.0f * 512.0f * 512.0f)));
}

extern "C" void kernel_launch(void* const* d_in, const int* in_sizes, int n_in,
                              void* d_out, int out_size, void* d_ws, size_t ws_size,
                              hipStream_t stream) {
  const float* x = (const float*)d_in[0];
  const float* y = (const float*)d_in[1];
  const float* gm = (const float*)d_in[2];
  float* out = (float*)d_out;
  float* ws = (float*)d_ws;   // 165 f32 + packed half2 tables (~2.1 KB)

  hipMemsetAsync(d_out, 0, out_size * sizeof(float), stream);
  prep_k<<<1, 256, 0, stream>>>(gm, ws);
  msloss_k<<<dim3(8, 16, 8), 256, 0, stream>>>(x, y, ws, out);
}

// Round 13
// 430.720 us; speedup vs baseline: 1.4757x; 1.2556x over previous
//
#include <hip/hip_runtime.h>

typedef _Float16 h2_t __attribute__((ext_vector_type(2)));

#define DI __device__ __forceinline__

#if __has_builtin(__builtin_amdgcn_sched_barrier)
#define SCHED_FENCE() __builtin_amdgcn_sched_barrier(0)
#else
#define SCHED_FENCE()
#endif

constexpr int PA = 98;           // staged tile pitch (halfs): 49 dwords, odd
constexpr int PB = 66;           // hb pitch (halfs): 33 dwords, odd
constexpr int TILE = 64 * PA;    // staged x/y tile: 64 rows x 96 cols (6272 h)
constexpr int HB = 64 * PB;      // hb map: 64 cols x 64 rows (4224 h)
constexpr float kC1 = 1.0e-4f;   // (0.01*1)^2
constexpr float kC2 = 9.0e-4f;   // (0.03*1)^2
constexpr float kALPHA = 0.025f;

DI float rcp_fast(float v) { return __builtin_amdgcn_rcpf(v); }

DI float fdot2f(h2_t a, h2_t b, float c) {
#if __has_builtin(__builtin_amdgcn_fdot2)
  return __builtin_amdgcn_fdot2(a, b, c, false);   // v_dot2_f32_f16
#else
  return c + (float)(a.x) * (float)(b.x) + (float)(a.y) * (float)(b.y);
#endif
}

DI h2_t ldh2(const _Float16* __restrict__ p) {
  return *reinterpret_cast<const h2_t*>(p);
}
DI h2_t w2h(unsigned u) { return __builtin_bit_cast(h2_t, u); }
DI h2_t pkabs(h2_t v) {
  unsigned u = __builtin_bit_cast(unsigned, v) & 0x7FFF7FFFu;
  return __builtin_bit_cast(h2_t, u);
}

// ---- horizontal conv: src[row][col] -> hb[col][row] ----
// Thread item = 1 row x 8 CONSECUTIVE cols [c0, c0+8): even cols use E table,
// odd cols use O table, BOTH at uniform addresses -> s_load -> SGPR weights.
// (R12's per-lane parity tables compiled to per-lane VMEM weight loads: 20+
// in-flight VGPRs + vmcnt stalls -> the 240 MB stat-array spill.)
// Window pairs for cols c0+2i / c0+2i+1 both span [pbase+i, pbase+i+R].
// MODE 0: conv(v).  MODE 1: conv(v^2).  MODE 2: conv(x*y).  MODE 3: conv(|x-y|).
template<int R, int MODE>
DI void hconv(const _Float16* __restrict__ src, _Float16* __restrict__ hb,
              const unsigned* __restrict__ E, const unsigned* __restrict__ O,
              int tid) {
  constexpr int NR = 32 + 2 * R;           // rows produced: [16-R, 48+R)
  constexpr int NG = NR * 8;               // 8 col-octets
  for (int g = tid; g < NG; g += 256) {
    const int row = (16 - R) + (g % NR);
    const int c0 = (g / NR) * 8;
    const int pbase = (c0 + 16 - R) >> 1;  // even
    const _Float16* px = src + row * PA + 2 * pbase;
    float a[8];
#pragma unroll
    for (int i = 0; i < 8; ++i) a[i] = 0.f;
#pragma unroll
    for (int p = 0; p < R + 4; ++p) {
      h2_t xq = ldh2(px + 2 * p);
      h2_t v;
      if (MODE == 0) v = xq;
      else if (MODE == 1) v = xq * xq;                 // v_pk_mul_f16
      else {
        h2_t yq = ldh2(px + 2 * p + TILE);
        v = (MODE == 2) ? (xq * yq) : pkabs(xq - yq);
      }
#pragma unroll
      for (int i = 0; i < 4; ++i) {
        const int j = p - i;
        if (j >= 0 && j <= R) {            // folds at compile time
          a[2 * i]     = fdot2f(w2h(E[j]), v, a[2 * i]);
          a[2 * i + 1] = fdot2f(w2h(O[j]), v, a[2 * i + 1]);
        }
      }
      if ((p & 7) == 7) SCHED_FENCE();
    }
    _Float16* wp = hb + c0 * PB + row;     // hb[col][row]
#pragma unroll
    for (int i = 0; i < 8; ++i) wp[i * PB] = (_Float16)a[i];
  }
}

// ---- vertical conv: 1 col x 8 CONSECUTIVE rows [r0, r0+8) ----
// Same E/O trick -> SGPR weights. col = tid&63 spreads banks (33 coprime 32).
template<int R>
DI void vconv(const _Float16* __restrict__ hb, const unsigned* __restrict__ E,
              const unsigned* __restrict__ O, int col, int r0,
              float* __restrict__ acc) {
  const int prow = (r0 + 16 - R) >> 1;
  const _Float16* p0 = hb + col * PB + 2 * prow;
#pragma unroll
  for (int p = 0; p < R + 4; ++p) {
    h2_t v = ldh2(p0 + 2 * p);
#pragma unroll
    for (int i = 0; i < 4; ++i) {
      const int j = p - i;
      if (j >= 0 && j <= R) {
        acc[2 * i]     = fdot2f(w2h(E[j]), v, acc[2 * i]);
        acc[2 * i + 1] = fdot2f(w2h(O[j]), v, acc[2 * i + 1]);
      }
    }
    if ((p & 7) == 7) SCHED_FENCE();
  }
}

// ---- vertical conv of |x-y| collapsed to scalar via single uniform U ----
template<int R>
DI float vl1(const _Float16* __restrict__ hb, const unsigned* __restrict__ U,
             int col, int r0) {
  const int prow = (r0 + 16 - R) >> 1;
  const _Float16* p0 = hb + col * PB + 2 * prow;
  float s = 0.f;
#pragma unroll
  for (int p = 0; p < R + 4; ++p)
    s = fdot2f(w2h(U[p]), ldh2(p0 + 2 * p), s);
  return s;
}

// Single-hb per-sigma pipeline: phases of hconv|bar|vconv|bar.
template<int R, bool LAST>
DI void do_sigma(int sidx, const unsigned* __restrict__ tabs0,
                 const _Float16* __restrict__ xt, _Float16* __restrict__ hb,
                 float* __restrict__ PIcs, float& gl1s, int tid) {
  const unsigned* E = tabs0 + sidx * 64;
  const unsigned* O = E + 32;
  const int col = tid & 63, r0 = (tid >> 6) * 8;

  float mux[8], muy[8], s2[8];
#pragma unroll
  for (int i = 0; i < 8; ++i) { mux[i] = 0.f; muy[i] = 0.f; s2[i] = 0.f; }

  hconv<R, 0>(xt, hb, E, O, tid);          // h(x)
  __syncthreads();
  vconv<R>(hb, E, O, col, r0, mux);
  __syncthreads();
  hconv<R, 1>(xt, hb, E, O, tid);          // h(x^2)
  __syncthreads();
  vconv<R>(hb, E, O, col, r0, s2);
  __syncthreads();
  hconv<R, 0>(xt + TILE, hb, E, O, tid);   // h(y)
  __syncthreads();
  vconv<R>(hb, E, O, col, r0, muy);
  __syncthreads();
  hconv<R, 1>(xt + TILE, hb, E, O, tid);   // h(y^2)
  __syncthreads();
  vconv<R>(hb, E, O, col, r0, s2);         // s2 = E[x^2]+E[y^2]
  __syncthreads();
  // fold in place: mux <- mxy, muy <- rden
#pragma unroll
  for (int i = 0; i < 8; ++i) {
    float a = mux[i], b = muy[i];
    float m2 = a * a + b * b;
    mux[i] = a * b;                        // mxy
    muy[i] = rcp_fast(s2[i] - m2 + kC2);   // rden
    if (LAST)                              // luminance folded into PIcs
      PIcs[i] *= fmaf(2.f, mux[i], kC1) * rcp_fast(m2 + kC1);
  }
  hconv<R, 2>(xt, hb, E, O, tid);          // h(x*y)
  __syncthreads();
  float exy[8];
#pragma unroll
  for (int i = 0; i < 8; ++i) exy[i] = 0.f;
  vconv<R>(hb, E, O, col, r0, exy);
  __syncthreads();
#pragma unroll
  for (int i = 0; i < 8; ++i)
    PIcs[i] *= fmaf(2.f, exy[i] - mux[i], kC2) * muy[i];
  if (LAST) {
    hconv<R, 3>(xt, hb, E, O, tid);        // h(|x-y|)
    __syncthreads();
    gl1s += vl1<R>(hb, tabs0 + 320, col, r0);
    __syncthreads();
  }
}

DI unsigned packh(float a, float b) {
  h2_t v; v.x = (_Float16)a; v.y = (_Float16)b;
  return __builtin_bit_cast(unsigned, v);
}

// ws: [0..164] f32 1D kernels; u32 tabs at +165: per sigma s: E @s*64+[0..R],
// O @s*64+32+[0..R]; single l1-collapse U table (R=16) @320+[0..19].
__global__ void prep_k(const float* __restrict__ gm, float* __restrict__ ws) {
  int t = threadIdx.x;
  if (t < 165) {
    int s = t / 33, j = t % 33;
    const float* m = gm + (3 * s) * (33 * 33);
    ws[t] = m[16 * 33 + j] / sqrtf(m[16 * 33 + 16]);
  }
  __syncthreads();
  if (t == 0) {
    unsigned* tabs = (unsigned*)(ws + 165);
    const int Rs[5] = {4, 6, 12, 16, 16};
    for (int s = 0; s < 5; ++s) {
      const int R = Rs[s];
      const float* w = ws + s * 33 + (16 - R);   // K = 2R+1 taps
      unsigned* E = tabs + s * 64;
      unsigned* O = E + 32;
      for (int i = 0; i < R; ++i) E[i] = packh(w[2 * i], w[2 * i + 1]);
      E[R] = packh(w[2 * R], 0.f);
      O[0] = packh(0.f, w[0]);
      for (int i = 1; i <= R; ++i) O[i] = packh(w[2 * i - 1], w[2 * i]);
    }
    // U[p] = sum over i=0..3, j=p-i in [0,16] of (E[j]+O[j]), sigma=8 (R=16)
    const float* w = ws + 4 * 33;
    unsigned* U = tabs + 320;
    for (int p = 0; p < 20; ++p) {
      float ux = 0.f, uy = 0.f;
      for (int i = 0; i < 4; ++i) {
        int j = p - i;
        if (j < 0 || j > 16) continue;
        ux += w[2 * j];                          // E[j].x
        if (2 * j + 1 <= 32) uy += w[2 * j + 1]; // E[j].y
        if (j > 0) ux += w[2 * j - 1];           // O[j].x
        uy += w[2 * j];                          // O[j].y
      }
      U[p] = packh(ux, uy);
    }
  }
}

// 64x32 output tile, 33.8 KB LDS -> 4 blocks/CU. (256,2) -> VGPR cap 128.
__global__ __launch_bounds__(256, 2)
void msloss_k(const float* __restrict__ x, const float* __restrict__ y,
              const float* __restrict__ ws, float* __restrict__ out) {
  // xt @0 [row][col] (64x96), yt @TILE, hb @2*TILE [col][row] (64x64)
  __shared__ __align__(16) _Float16 smem[2 * TILE + HB];
  __shared__ float red[4];
  _Float16* xt = smem;
  _Float16* hb = smem + 2 * TILE;
  const unsigned* tabs0 = (const unsigned*)(ws + 165);
  const int tid = threadIdx.x;
  const int ox = blockIdx.x * 64, oy = blockIdx.y * 32;
  const int b = blockIdx.z;

  float PIcs[8];
  float gl1s = 0.f;
#pragma unroll
  for (int i = 0; i < 8; ++i) PIcs[i] = 1.f;

  for (int c = 0; c < 3; ++c) {
    const float* xp = x + (size_t)(b * 3 + c) * (512 * 512);
    const float* yp = y + (size_t)(b * 3 + c) * (512 * 512);
    // stage 64 rows x 96 cols fp32 -> fp16, [row][col], zero halo
#pragma unroll
    for (int it = 0; it < 12; ++it) {
      int idx = it * 256 + tid;            // 64 rows x 48 colpairs
      int row = idx / 48, cp = idx % 48;
      int gy = oy + row - 16, gx = ox + cp * 2 - 16;
      bool ok = ((unsigned)gy < 512u) && ((unsigned)gx < 512u);  // gx even
      float2 xv = make_float2(0.f, 0.f), yv = make_float2(0.f, 0.f);
      if (ok) {
        xv = *reinterpret_cast<const float2*>(xp + gy * 512 + gx);
        yv = *reinterpret_cast<const float2*>(yp + gy * 512 + gx);
      }
      h2_t hx; hx.x = (_Float16)xv.x; hx.y = (_Float16)xv.y;
      h2_t hy; hy.x = (_Float16)yv.x; hy.y = (_Float16)yv.y;
      *reinterpret_cast<h2_t*>(xt + row * PA + cp * 2) = hx;
      *reinterpret_cast<h2_t*>(xt + TILE + row * PA + cp * 2) = hy;
    }
    __syncthreads();
    do_sigma<4,  false>(0, tabs0, xt, hb, PIcs, gl1s, tid);
    do_sigma<6,  false>(1, tabs0, xt, hb, PIcs, gl1s, tid);
    do_sigma<12, false>(2, tabs0, xt, hb, PIcs, gl1s, tid);
    do_sigma<16, false>(3, tabs0, xt, hb, PIcs, gl1s, tid);
    do_sigma<16, true >(4, tabs0, xt, hb, PIcs, gl1s, tid);
    // do_sigma ends with __syncthreads(): safe to restage next channel
  }

  float s = ((1.f - kALPHA) / 3.f) * gl1s;
#pragma unroll
  for (int i = 0; i < 8; ++i) s += kALPHA * (1.f - PIcs[i]);
#pragma unroll
  for (int off = 32; off > 0; off >>= 1) s += __shfl_down(s, off);
  if ((tid & 63) == 0) red[tid >> 6] = s;
  __syncthreads();
  if (tid == 0)
    atomicAdd(out, (red[0] + red[1] + red[2] + red[3]) *
                       (200.0f / (8.0f * 512.0f * 512.0f)));
}

extern "C" void kernel_launch(void* const* d_in, const int* in_sizes, int n_in,
                              void* d_out, int out_size, void* d_ws, size_t ws_size,
                              hipStream_t stream) {
  const float* x = (const float*)d_in[0];
  const float* y = (const float*)d_in[1];
  const float* gm = (const float*)d_in[2];
  float* out = (float*)d_out;
  float* ws = (float*)d_ws;   // 165 f32 + packed half2 tables (~1.6 KB)

  hipMemsetAsync(d_out, 0, out_size * sizeof(float), stream);
  prep_k<<<1, 256, 0, stream>>>(gm, ws);
  msloss_k<<<dim3(8, 16, 8), 256, 0, stream>>>(x, y, ws, out);
}